// Round 7
// baseline (50.027 us; speedup 1.0000x reference)
//
#include <hip/hip_runtime.h>

// Problem constants: B=8192, NJ=14, COL=14, sigma=1, radius=4.
#define NJ    14
#define TILE  196            // floats per tile (= 49 float4, 784 B)
#define BLK   256
#define JPB   32             // joints (tiles) per block; 8 threads per tile
#define N4    (JPB * 49)     // 1568 float4 staged per block (25088 B)

typedef __attribute__((address_space(1))) const void g_void;
typedef __attribute__((address_space(3))) void lds_void;

// exp(-0.5*d*d) with the 9-tap cutoff (|d|<=4), via v_exp_f32.
__device__ __forceinline__ float gtap(int d) {
  const int d2 = d * d;
  const float e = exp2f(-0.72134752044448169f * (float)d2);  // 0.5*log2(e)
  return (d2 <= 16) ? e : 0.0f;
}

// 1-D blurred-impulse response at position p for peak pk, with scipy
// 'reflect' padding folded in. Unnormalized (kernel-sum cancels in g/max).
__device__ __forceinline__ float uresp(int p, int pk) {
  float s = gtap(p - pk);
  if (p <= 3)  s += gtap(p + pk + 1);   // low reflection  (q<0 -> -1-q)
  if (p >= 10) s += gtap(27 - p - pk);  // high reflection (q>13 -> 27-q)
  return s;
}

__device__ __forceinline__ float wave_sum(float x) {
#pragma unroll
  for (int off = 32; off >= 1; off >>= 1) x += __shfl_xor(x, off);
  return x;
}

// Part P of one tile: float4 indices f = 8i + P (49 = 7 + 6*7).
// All element indices compile-time -> uy/ux stay in registers (rule #20).
template<int P>
__device__ __forceinline__ void accum_part(const float4* __restrict__ hp,
    const float (&uy)[14], const float (&ux)[14],
    float& bm, int& bi, float& sh2, float& cross, float& q0)
{
  const int NI = (P == 0) ? 7 : 6;
#pragma unroll
  for (int i = 0; i < NI; ++i) {
    const int f = 8 * i + P;
    const float4 q = hp[f];            // ds_read_b128
    const float qa[4] = {q.x, q.y, q.z, q.w};
#pragma unroll
    for (int c = 0; c < 4; ++c) {
      const int idx = 4 * f + c;
      const int y = idx / 14;
      const int x = idx - 14 * y;            // compile-time
      const float hv = qa[c];
      if (hv > bm) { bm = hv; bi = idx; }    // first-index within part
      sh2 = fmaf(hv, hv, sh2);
      if (y == 0) q0 = fmaf(hv, hv, q0);     // row-0 energy (invis fixup)
      cross = fmaf(hv, uy[y] * ux[x], cross);
    }
  }
}

__global__ __launch_bounds__(BLK, 6) void joint_kernel(
    const float* __restrict__ o, const float* __restrict__ h,
    const float* __restrict__ t, const float* __restrict__ v,
    float* __restrict__ part, int njoint, int nblocks)
{
  // 25088 B stage buffer; aliased for the cross-wave combine after a barrier.
  __shared__ __align__(16) float lds[N4 * 4];

  const int tid  = threadIdx.x;
  const int lane = tid & 63;
  const int wid  = tid >> 6;
  const int tl   = tid & 31;                   // this thread's tile 0..31
  const int jg   = blockIdx.x * JPB + tl;      // its joint (grid exact: 3584*32)

  // ---- coalesced global->LDS stage of this block's 32 tiles ----
  const float* gbase = h + (size_t)blockIdx.x * JPB * TILE;
#pragma unroll
  for (int i = 0; i < 7; ++i) {
    const int idx = i * BLK + tid;
    if (idx < N4) {
      __builtin_amdgcn_global_load_lds(
          (g_void*)(gbase + (size_t)idx * 4),       // per-lane global src
          (lds_void*)&lds[idx * 4],                 // uniform base + lane*16
          16, 0, 0);
    }
  }

  // ---- overlap: analytic 1-D responses while loads fly ----
  float uy[14], ux[14];
  const float2 tv = ((const float2*)t)[jg];
  const int xi = min(max((int)(tv.x * 14.0f), 0), 13);
  const int yi = min(max((int)(tv.y * 14.0f), 0), 13);
#pragma unroll
  for (int p = 0; p < 14; ++p) { uy[p] = uresp(p, yi); ux[p] = uresp(p, xi); }

  asm volatile("s_waitcnt vmcnt(0)" ::: "memory");
  __syncthreads();

  // ---- part pass: wave-uniform wid + single 2-way lane-half branch ----
  float bm = -3.0e38f; int bi = 0;
  float sh2 = 0.0f, cross = 0.0f, q0 = 0.0f;
  {
    const float4* hp = (const float4*)&lds[tl * TILE];
    switch (wid) {
      case 0:  if (lane < 32) accum_part<0>(hp, uy, ux, bm, bi, sh2, cross, q0);
               else           accum_part<1>(hp, uy, ux, bm, bi, sh2, cross, q0); break;
      case 1:  if (lane < 32) accum_part<2>(hp, uy, ux, bm, bi, sh2, cross, q0);
               else           accum_part<3>(hp, uy, ux, bm, bi, sh2, cross, q0); break;
      case 2:  if (lane < 32) accum_part<4>(hp, uy, ux, bm, bi, sh2, cross, q0);
               else           accum_part<5>(hp, uy, ux, bm, bi, sh2, cross, q0); break;
      default: if (lane < 32) accum_part<6>(hp, uy, ux, bm, bi, sh2, cross, q0);
               else           accum_part<7>(hp, uy, ux, bm, bi, sh2, cross, q0); break;
    }
  }

  // ---- combine the two lane-half parts (global first-index tie-break) ----
  {
    const float om = __shfl_xor(bm, 32);
    const int   oi = __shfl_xor(bi, 32);
    if (om > bm || (om == bm && oi < bi)) { bm = om; bi = oi; }
    sh2   += __shfl_xor(sh2, 32);
    cross += __shfl_xor(cross, 32);
    q0    += __shfl_xor(q0, 32);
  }

  __syncthreads();   // all waves done READING tiles; safe to alias LDS
  // per-wave combined partials: 5 arrays x [4 waves][32 tiles] = 2560 B
  if (lane < 32) {
    lds[(0 * 4 + wid) * 32 + tl] = bm;
    ((int*)lds)[(1 * 4 + wid) * 32 + tl] = bi;
    lds[(2 * 4 + wid) * 32 + tl] = sh2;
    lds[(3 * 4 + wid) * 32 + tl] = cross;
    lds[(4 * 4 + wid) * 32 + tl] = q0;
  }
  __syncthreads();

  float s_acc = 0.0f, n_acc = 0.0f;
  if (wid == 0) {
    if (lane < 32) {
      float Bm = lds[0 * 128 + lane];
      int   Bi = ((int*)lds)[1 * 128 + lane];
      float S2 = lds[2 * 128 + lane];
      float Cr = lds[3 * 128 + lane];
      float Q0 = lds[4 * 128 + lane];
#pragma unroll
      for (int w = 1; w < 4; ++w) {
        const float m = lds[0 * 128 + w * 32 + lane];
        const int   i = ((int*)lds)[1 * 128 + w * 32 + lane];
        if (m > Bm || (m == Bm && i < Bi)) { Bm = m; Bi = i; }
        S2 += lds[2 * 128 + w * 32 + lane];
        Cr += lds[3 * 128 + w * 32 + lane];
        Q0 += lds[4 * 128 + w * 32 + lane];
      }

      const float2 vv = ((const float2*)v)[jg];
      const bool vis = ((int)vv.x) == 1;

      float Sy2 = 0.0f, Sx2 = 0.0f;
#pragma unroll
      for (int p = 0; p < 14; ++p) {
        Sy2 = fmaf(uy[p], uy[p], Sy2);
        Sx2 = fmaf(ux[p], ux[p], Sx2);
      }
      const float maxy = 1.0f + gtap(2 * yi + 1) + gtap(27 - 2 * yi);
      const float maxx = 1.0f + gtap(2 * xi + 1) + gtap(27 - 2 * xi);
      const float inv = vis ? (1.0f / (maxy * maxx)) : 0.0f;

      // sum(h-tt)^2 = S2 - 2*inv*Cr + inv^2*Sy2*Sx2 ; row0 zeroed if invis
      float s = S2 - 2.0f * inv * Cr + inv * inv * Sy2 * Sx2;
      if (!vis) s -= Q0;

      // ---- coordinate loss (argmax-dependent gather, stays global) ----
      const int b = jg / NJ;
      const int j = jg - b * NJ;
      const int yC = Bi / 14;
      const int xC = Bi - 14 * yC;
      const size_t ob = ((size_t)b * (2 * NJ) + j) * TILE + (size_t)Bi;
      const float ox = o[ob];
      const float oy = o[ob + (size_t)NJ * TILE];
      const bool cond = Bm > 0.5f;
      const float sc = 1.0f / 14.0f;
      const float px = cond ? (ox + (float)xC) * sc : 0.0f;
      const float py = cond ? (oy + (float)yC) * sc : 0.0f;
      const float d0 = (px - tv.x) * vv.x;
      const float d1 = (py - tv.y) * vv.y;
      s += d0 * d0 + d1 * d1;

      s_acc = s;
      n_acc = vv.x + vv.y;
    }
    // ---- deterministic wave-0 reduction -> per-block partial ----
    s_acc = wave_sum(s_acc);
    n_acc = wave_sum(n_acc);
    if (lane == 0) {
      part[blockIdx.x]           = s_acc;
      part[nblocks + blockIdx.x] = n_acc;
    }
  }
}

#define FBLK 1024
__global__ __launch_bounds__(FBLK) void finalize_kernel(
    const float* __restrict__ part, float* __restrict__ out, int nblocks)
{
  float s = 0.0f, n = 0.0f;
  for (int i = threadIdx.x; i < nblocks; i += FBLK) {
    s += part[i];
    n += part[nblocks + i];
  }
  s = wave_sum(s);
  n = wave_sum(n);
  __shared__ float rs[16], rn[16];
  const int lane = threadIdx.x & 63, wid = threadIdx.x >> 6;
  if (lane == 0) { rs[wid] = s; rn[wid] = n; }
  __syncthreads();
  if (threadIdx.x == 0) {
    float S = 0.0f, N = 0.0f;
#pragma unroll
    for (int i = 0; i < 16; ++i) { S += rs[i]; N += rn[i]; }
    out[0] = S / (0.5f * N);   // (d1_sum + d2_sum) / N1, N1 = sum(v)/2
  }
}

extern "C" void kernel_launch(void* const* d_in, const int* in_sizes, int n_in,
                              void* d_out, int out_size, void* d_ws, size_t ws_size,
                              hipStream_t stream)
{
  const float* o = (const float*)d_in[0];  // [B, 2*NJ, 14, 14]
  const float* h = (const float*)d_in[1];  // [B, NJ, 14, 14]
  const float* t = (const float*)d_in[2];  // [B, NJ, 2]
  const float* v = (const float*)d_in[3];  // [B, NJ, 2]
  const int njoint = in_sizes[1] / TILE;   // B*NJ = 114688 (divisible by 32)
  const int nblocks = njoint / JPB;        // 3584

  float* part = (float*)d_ws;  // 2*nblocks floats = 28 KB, rewritten each call
  joint_kernel<<<nblocks, BLK, 0, stream>>>(o, h, t, v, part, njoint, nblocks);
  finalize_kernel<<<1, FBLK, 0, stream>>>(part, (float*)d_out, nblocks);
}

// Round 8
// 35.277 us; speedup vs baseline: 1.4181x; 1.4181x over previous
//
#include <hip/hip_runtime.h>

// Problem constants: B=8192, NJ=14, COL=14, sigma=1, radius=4.
#define NJ    14
#define TILE  196            // floats per tile (= 49 float4, 784 B)
#define BLK   256
#define JPC   64             // joints per chunk (one tile per lane)
#define N4C   (JPC * 49)     // 3136 float4 per chunk (50176 B)
#define NCH   7              // chunks per block
#define JPB   (JPC * NCH)    // 448 joints per block
#define GRID  256            // 1 persistent block per CU; 256*448 = 114688 exact

typedef __attribute__((address_space(1))) const void g_void;
typedef __attribute__((address_space(3))) void lds_void;

// exp(-0.5*d*d) with the 9-tap cutoff (|d|<=4), via v_exp_f32.
__device__ __forceinline__ float gtap(int d) {
  const int d2 = d * d;
  const float e = exp2f(-0.72134752044448169f * (float)d2);  // 0.5*log2(e)
  return (d2 <= 16) ? e : 0.0f;
}

// 1-D blurred-impulse response at position p for peak pk, with scipy
// 'reflect' padding folded in. Unnormalized (kernel-sum cancels in g/max).
__device__ __forceinline__ float uresp(int p, int pk) {
  float s = gtap(p - pk);
  if (p <= 3)  s += gtap(p + pk + 1);   // low reflection  (q<0 -> -1-q)
  if (p >= 10) s += gtap(27 - p - pk);  // high reflection (q>13 -> 27-q)
  return s;
}

__device__ __forceinline__ float wave_sum(float x) {
#pragma unroll
  for (int off = 32; off >= 1; off >>= 1) x += __shfl_xor(x, off);
  return x;
}

// Quarter K of one tile: float4 indices f = 4i + K (49 = 13+12+12+12).
// All element indices compile-time -> uy/ux stay in registers (rule #20).
template<int K>
__device__ __forceinline__ void accum_part(const float4* __restrict__ hp,
    const float (&uy)[14], const float (&ux)[14],
    float& bm, int& bi, float& sh2, float& cross, float& q0)
{
  const int NI = (K == 0) ? 13 : 12;
#pragma unroll
  for (int i = 0; i < NI; ++i) {
    const int f = 4 * i + K;
    const float4 q = hp[f];            // ds_read_b128
    const float qa[4] = {q.x, q.y, q.z, q.w};
#pragma unroll
    for (int c = 0; c < 4; ++c) {
      const int idx = 4 * f + c;
      const int y = idx / 14;
      const int x = idx - 14 * y;            // compile-time
      const float hv = qa[c];
      if (hv > bm) { bm = hv; bi = idx; }    // first-index within quarter
      sh2 = fmaf(hv, hv, sh2);
      if (y == 0) q0 = fmaf(hv, hv, q0);     // row-0 energy (invis fixup)
      cross = fmaf(hv, uy[y] * ux[x], cross);
    }
  }
}

// Stage one 64-tile chunk (3136 float4) into LDS. Per-wave instruction
// counts: wave0 = 13, waves 1-3 = 12 (3136 = 12*256 + 64). These counts
// are what the counted vmcnt waits below rely on.
__device__ __forceinline__ void stage_chunk(const float* __restrict__ h,
    size_t jbase, int c, float* dst, int tid, int wid, int lane)
{
  const float* gsrc = h + (jbase + (size_t)c * JPC) * TILE;
#pragma unroll
  for (int i = 0; i < 12; ++i) {
    const int idx = i * BLK + tid;
    __builtin_amdgcn_global_load_lds(
        (g_void*)(gsrc + (size_t)idx * 4),
        (lds_void*)(dst + (size_t)idx * 4), 16, 0, 0);
  }
  if (wid == 0) {
    const int idx = 12 * BLK + lane;
    __builtin_amdgcn_global_load_lds(
        (g_void*)(gsrc + (size_t)idx * 4),
        (lds_void*)(dst + (size_t)idx * 4), 16, 0, 0);
  }
}

__global__ __launch_bounds__(BLK) void joint_kernel(
    const float* __restrict__ o, const float* __restrict__ h,
    const float* __restrict__ t, const float* __restrict__ v,
    float* __restrict__ part)
{
  __shared__ __align__(16) float bufA[N4C * 4];   // 50176 B
  __shared__ __align__(16) float bufB[N4C * 4];   // 50176 B
  __shared__ float pf[2][4][4][JPC];              // parity/field/wave/lane
  __shared__ int   pib[2][4][JPC];
  __shared__ __align__(16) float tlds[JPB * 2];   // 3584 B
  __shared__ __align__(16) float vlds[JPB * 2];   // 3584 B

  const int tid  = threadIdx.x;
  const int lane = tid & 63;
  const int wid  = tid >> 6;
  const size_t jbase = (size_t)blockIdx.x * JPB;

  // ---- prologue: stage t/v (1 instr each per wave -> oldest, retire first) ----
  if (tid < JPB * 2 / 4) {   // 224 float4 cover 448 joints * 2 floats
    __builtin_amdgcn_global_load_lds(
        (g_void*)(t + jbase * 2 + (size_t)tid * 4), (lds_void*)&tlds[tid * 4], 16, 0, 0);
    __builtin_amdgcn_global_load_lds(
        (g_void*)(v + jbase * 2 + (size_t)tid * 4), (lds_void*)&vlds[tid * 4], 16, 0, 0);
  }
  // ---- stage chunks 0 and 1 (both buffers in flight) ----
  stage_chunk(h, jbase, 0, bufA, tid, wid, lane);
  stage_chunk(h, jbase, 1, bufB, tid, wid, lane);

  float s_acc = 0.0f, n_acc = 0.0f;

  for (int k = 0; k < NCH; ++k) {
    // ---- counted wait: chunk k arrived; chunk k+1 stays in flight ----
    if (k == NCH - 1)    asm volatile("s_waitcnt vmcnt(0)" ::: "memory");
    else if (wid == 0)   asm volatile("s_waitcnt vmcnt(13)" ::: "memory");
    else                 asm volatile("s_waitcnt vmcnt(12)" ::: "memory");
    __builtin_amdgcn_s_barrier();
    asm volatile("" ::: "memory");

    // ---- per-joint analytic responses (t from LDS: no vmcnt pollution) ----
    const int jl = k * JPC + lane;
    const float2 tv = *(const float2*)&tlds[jl * 2];
    const int xi = min(max((int)(tv.x * 14.0f), 0), 13);
    const int yi = min(max((int)(tv.y * 14.0f), 0), 13);
    float uy[14], ux[14];
#pragma unroll
    for (int p = 0; p < 14; ++p) { uy[p] = uresp(p, yi); ux[p] = uresp(p, xi); }

    // ---- quarter pass over this lane's tile (divergence-free) ----
    const float* bsrc = (k & 1) ? bufB : bufA;
    const float4* hp = (const float4*)(bsrc + lane * TILE);
    float bm = -3.0e38f; int bi = 0;
    float sh2 = 0.0f, cross = 0.0f, q0 = 0.0f;
    switch (wid) {
      case 0:  accum_part<0>(hp, uy, ux, bm, bi, sh2, cross, q0); break;
      case 1:  accum_part<1>(hp, uy, ux, bm, bi, sh2, cross, q0); break;
      case 2:  accum_part<2>(hp, uy, ux, bm, bi, sh2, cross, q0); break;
      default: accum_part<3>(hp, uy, ux, bm, bi, sh2, cross, q0); break;
    }

    // ---- publish quarter partials (parity-buffered) ----
    const int par = k & 1;
    pf[par][0][wid][lane] = bm;
    pib[par][wid][lane]   = bi;
    pf[par][1][wid][lane] = sh2;
    pf[par][2][wid][lane] = cross;
    pf[par][3][wid][lane] = q0;
    asm volatile("s_waitcnt lgkmcnt(0)" ::: "memory");
    __builtin_amdgcn_s_barrier();     // partials visible; compute buffer free
    asm volatile("" ::: "memory");

    // ---- wave0 epilogue for chunk k (runs in other waves' HBM slack) ----
    if (wid == 0) {
      float Bm = pf[par][0][0][lane]; int Bi = pib[par][0][lane];
      float S2 = pf[par][1][0][lane];
      float Cr = pf[par][2][0][lane];
      float Q0 = pf[par][3][0][lane];
#pragma unroll
      for (int w = 1; w < 4; ++w) {
        const float m = pf[par][0][w][lane];
        const int   i = pib[par][w][lane];
        if (m > Bm || (m == Bm && i < Bi)) { Bm = m; Bi = i; }  // global first-index
        S2 += pf[par][1][w][lane];
        Cr += pf[par][2][w][lane];
        Q0 += pf[par][3][w][lane];
      }

      const float2 vv = *(const float2*)&vlds[jl * 2];
      const bool vis = ((int)vv.x) == 1;

      float Sy2 = 0.0f, Sx2 = 0.0f;
#pragma unroll
      for (int p = 0; p < 14; ++p) {
        Sy2 = fmaf(uy[p], uy[p], Sy2);
        Sx2 = fmaf(ux[p], ux[p], Sx2);
      }
      const float maxy = 1.0f + gtap(2 * yi + 1) + gtap(27 - 2 * yi);
      const float maxx = 1.0f + gtap(2 * xi + 1) + gtap(27 - 2 * xi);
      const float inv = vis ? (1.0f / (maxy * maxx)) : 0.0f;

      // sum(h-tt)^2 = S2 - 2*inv*Cr + inv^2*Sy2*Sx2 ; row0 zeroed if invis
      float s = S2 - 2.0f * inv * Cr + inv * inv * Sy2 * Sx2;
      if (!vis) s -= Q0;

      // coordinate loss (argmax-dependent gather; wave0's vmcnt(0) here only
      // waits on o + the long-retired chunk k+1 stage loads)
      const int jg = (int)jbase + jl;
      const int b = jg / NJ;
      const int j = jg - b * NJ;
      const int yC = Bi / 14;
      const int xC = Bi - 14 * yC;
      const size_t ob = ((size_t)b * (2 * NJ) + j) * TILE + (size_t)Bi;
      const float ox = o[ob];
      const float oy = o[ob + (size_t)NJ * TILE];
      const bool cond = Bm > 0.5f;
      const float sc = 1.0f / 14.0f;
      const float px = cond ? (ox + (float)xC) * sc : 0.0f;
      const float py = cond ? (oy + (float)yC) * sc : 0.0f;
      const float d0 = (px - tv.x) * vv.x;
      const float d1 = (py - tv.y) * vv.y;
      s += d0 * d0 + d1 * d1;

      s_acc += s;
      n_acc += vv.x + vv.y;
      // materialize before staging so the o-wait can't slide past stage issue
      asm volatile("" : "+v"(s_acc), "+v"(n_acc));
    }

    // ---- issue stage for chunk k+2 into the buffer just freed ----
    if (k + 2 < NCH) {
      stage_chunk(h, jbase, k + 2, (k & 1) ? bufB : bufA, tid, wid, lane);
    }
  }

  // ---- per-block deterministic result (wave0 only; no barrier needed) ----
  if (wid == 0) {
    const float S = wave_sum(s_acc);
    const float N = wave_sum(n_acc);
    if (lane == 0) {
      part[blockIdx.x]        = S;
      part[GRID + blockIdx.x] = N;
    }
  }
}

__global__ __launch_bounds__(BLK) void finalize_kernel(
    const float* __restrict__ part, float* __restrict__ out)
{
  // 2*GRID = 512 partials; one per thread
  const int tid = threadIdx.x;
  float s = part[tid];
  float n = part[GRID + tid];
  s = wave_sum(s);
  n = wave_sum(n);
  __shared__ float rs[4], rn[4];
  const int lane = tid & 63, wid = tid >> 6;
  if (lane == 0) { rs[wid] = s; rn[wid] = n; }
  __syncthreads();
  if (tid == 0) {
    const float S = rs[0] + rs[1] + rs[2] + rs[3];
    const float N = rn[0] + rn[1] + rn[2] + rn[3];
    out[0] = S / (0.5f * N);   // (d1_sum + d2_sum) / N1, N1 = sum(v)/2
  }
}

extern "C" void kernel_launch(void* const* d_in, const int* in_sizes, int n_in,
                              void* d_out, int out_size, void* d_ws, size_t ws_size,
                              hipStream_t stream)
{
  const float* o = (const float*)d_in[0];  // [B, 2*NJ, 14, 14]
  const float* h = (const float*)d_in[1];  // [B, NJ, 14, 14]
  const float* t = (const float*)d_in[2];  // [B, NJ, 2]
  const float* v = (const float*)d_in[3];  // [B, NJ, 2]

  float* part = (float*)d_ws;  // 2*GRID floats = 2 KB, fully rewritten each call
  joint_kernel<<<GRID, BLK, 0, stream>>>(o, h, t, v, part);
  finalize_kernel<<<1, BLK, 0, stream>>>(part, (float*)d_out);
}

// Round 9
// 34.718 us; speedup vs baseline: 1.4409x; 1.0161x over previous
//
#include <hip/hip_runtime.h>

// Problem constants: B=8192, NJ=14, COL=14, sigma=1, radius=4.
#define NJ    14
#define TILE  196            // floats per tile (= 49 float4, 784 B)
#define BLK   256
#define JPB   64             // joints per block: lane = tile, wave = quarter

// exp(-0.5*d*d) with the 9-tap cutoff (|d|<=4), via v_exp_f32.
__device__ __forceinline__ float gtap(int d) {
  const int d2 = d * d;
  const float e = exp2f(-0.72134752044448169f * (float)d2);  // 0.5*log2(e)
  return (d2 <= 16) ? e : 0.0f;
}

// 1-D blurred-impulse response at position p for peak pk, with scipy
// 'reflect' padding folded in. Unnormalized (kernel-sum cancels in g/max).
__device__ __forceinline__ float uresp(int p, int pk) {
  float s = gtap(p - pk);
  if (p <= 3)  s += gtap(p + pk + 1);   // low reflection  (q<0 -> -1-q)
  if (p >= 10) s += gtap(27 - p - pk);  // high reflection (q>13 -> 27-q)
  return s;
}

__device__ __forceinline__ float wave_sum(float x) {
#pragma unroll
  for (int off = 32; off >= 1; off >>= 1) x += __shfl_xor(x, off);
  return x;
}

// Quarter K of one tile: float4 indices f = 4i + K (49 = 13+12+12+12).
// hp points at this lane's tile in GLOBAL memory (16B-aligned: 784 = 49*16).
// 13 independent global_load_dwordx4 -> compiler overlaps their latency.
// All element indices compile-time -> uy/ux stay in registers (rule #20).
template<int K>
__device__ __forceinline__ void accum_part(const float4* __restrict__ hp,
    const float (&uy)[14], const float (&ux)[14],
    float& bm, int& bi, float& sh2, float& cross, float& q0)
{
  const int NI = (K == 0) ? 13 : 12;
#pragma unroll
  for (int i = 0; i < NI; ++i) {
    const int f = 4 * i + K;
    const float4 q = hp[f];
    const float qa[4] = {q.x, q.y, q.z, q.w};
#pragma unroll
    for (int c = 0; c < 4; ++c) {
      const int idx = 4 * f + c;
      const int y = idx / 14;
      const int x = idx - 14 * y;            // compile-time
      const float hv = qa[c];
      if (hv > bm) { bm = hv; bi = idx; }    // first-index within quarter
      sh2 = fmaf(hv, hv, sh2);
      if (y == 0) q0 = fmaf(hv, hv, q0);     // row-0 energy (invis fixup)
      cross = fmaf(hv, uy[y] * ux[x], cross);
    }
  }
}

__global__ __launch_bounds__(BLK, 4) void joint_kernel(
    const float* __restrict__ o, const float* __restrict__ h,
    const float* __restrict__ t, const float* __restrict__ v,
    float* __restrict__ part, int njoint, int nblocks)
{
  // small combine arrays only (~6KB LDS) -> occupancy is VGPR-bound
  __shared__ float sm_bm[4][JPB];
  __shared__ int   sm_bi[4][JPB];
  __shared__ float sm_s2[4][JPB];
  __shared__ float sm_cr[4][JPB];
  __shared__ float sm_q0[4][JPB];

  const int lane = threadIdx.x & 63;
  const int wid  = threadIdx.x >> 6;
  const int jg   = blockIdx.x * JPB + lane;     // grid exact: 1792*64 = 114688
  const bool valid = jg < njoint;

  float uy[14], ux[14];
  float bm = -3.0e38f; int bi = 0;
  float sh2 = 0.0f, cross = 0.0f, q0 = 0.0f;
  float2 tv = make_float2(0.0f, 0.0f);
  int xi = 0, yi = 0;

  if (valid) {
    tv = ((const float2*)t)[jg];
    xi = min(max((int)(tv.x * 14.0f), 0), 13);
    yi = min(max((int)(tv.y * 14.0f), 0), 13);
#pragma unroll
    for (int p = 0; p < 14; ++p) { uy[p] = uresp(p, yi); ux[p] = uresp(p, xi); }

    const float4* hp = (const float4*)(h + (size_t)jg * TILE);
    switch (wid) {   // wave-uniform branch: no lane divergence
      case 0: accum_part<0>(hp, uy, ux, bm, bi, sh2, cross, q0); break;
      case 1: accum_part<1>(hp, uy, ux, bm, bi, sh2, cross, q0); break;
      case 2: accum_part<2>(hp, uy, ux, bm, bi, sh2, cross, q0); break;
      default: accum_part<3>(hp, uy, ux, bm, bi, sh2, cross, q0); break;
    }
  }

  sm_bm[wid][lane] = bm;  sm_bi[wid][lane] = bi;
  sm_s2[wid][lane] = sh2; sm_cr[wid][lane] = cross; sm_q0[wid][lane] = q0;
  __syncthreads();

  if (wid == 0) {
    // ---- combine the 4 quarters for this lane's joint ----
    float Bm = sm_bm[0][lane]; int Bi = sm_bi[0][lane];
    float S2 = sm_s2[0][lane], Cr = sm_cr[0][lane], Q0 = sm_q0[0][lane];
#pragma unroll
    for (int w = 1; w < 4; ++w) {
      const float m = sm_bm[w][lane]; const int i = sm_bi[w][lane];
      if (m > Bm || (m == Bm && i < Bi)) { Bm = m; Bi = i; }  // global first-index
      S2 += sm_s2[w][lane]; Cr += sm_cr[w][lane]; Q0 += sm_q0[w][lane];
    }

    float s_acc = 0.0f, n_acc = 0.0f;
    if (valid) {
      const float2 vv = ((const float2*)v)[jg];
      const bool vis = ((int)vv.x) == 1;

      float Sy2 = 0.0f, Sx2 = 0.0f;
#pragma unroll
      for (int p = 0; p < 14; ++p) {
        Sy2 = fmaf(uy[p], uy[p], Sy2);
        Sx2 = fmaf(ux[p], ux[p], Sx2);
      }
      const float maxy = 1.0f + gtap(2 * yi + 1) + gtap(27 - 2 * yi);
      const float maxx = 1.0f + gtap(2 * xi + 1) + gtap(27 - 2 * xi);
      const float inv = vis ? (1.0f / (maxy * maxx)) : 0.0f;

      // sum(h-tt)^2 = S2 - 2*inv*Cr + inv^2*Sy2*Sx2 ; row0 zeroed if invis
      float s = S2 - 2.0f * inv * Cr + inv * inv * Sy2 * Sx2;
      if (!vis) s -= Q0;

      // ---- coordinate loss (argmax-dependent gather) ----
      const int b = jg / NJ;
      const int j = jg - b * NJ;
      const int yC = Bi / 14;
      const int xC = Bi - 14 * yC;
      const size_t ob = ((size_t)b * (2 * NJ) + j) * TILE + (size_t)Bi;
      const float ox = o[ob];
      const float oy = o[ob + (size_t)NJ * TILE];
      const bool cond = Bm > 0.5f;
      const float sc = 1.0f / 14.0f;
      const float px = cond ? (ox + (float)xC) * sc : 0.0f;
      const float py = cond ? (oy + (float)yC) * sc : 0.0f;
      const float d0 = (px - tv.x) * vv.x;
      const float d1 = (py - tv.y) * vv.y;
      s += d0 * d0 + d1 * d1;

      s_acc = s;
      n_acc = vv.x + vv.y;
    }

    // ---- deterministic wave-0 reduction -> per-block partial ----
    s_acc = wave_sum(s_acc);
    n_acc = wave_sum(n_acc);
    if (lane == 0) {
      part[blockIdx.x]           = s_acc;
      part[nblocks + blockIdx.x] = n_acc;
    }
  }
}

__global__ __launch_bounds__(BLK) void finalize_kernel(
    const float* __restrict__ part, float* __restrict__ out, int nblocks)
{
  float s = 0.0f, n = 0.0f;
  for (int i = threadIdx.x; i < nblocks; i += BLK) {
    s += part[i];
    n += part[nblocks + i];
  }
  s = wave_sum(s);
  n = wave_sum(n);
  __shared__ float rs[4], rn[4];
  const int lane = threadIdx.x & 63, wid = threadIdx.x >> 6;
  if (lane == 0) { rs[wid] = s; rn[wid] = n; }
  __syncthreads();
  if (threadIdx.x == 0) {
    const float S = rs[0] + rs[1] + rs[2] + rs[3];
    const float N = rn[0] + rn[1] + rn[2] + rn[3];
    out[0] = S / (0.5f * N);   // (d1_sum + d2_sum) / N1, N1 = sum(v)/2
  }
}

extern "C" void kernel_launch(void* const* d_in, const int* in_sizes, int n_in,
                              void* d_out, int out_size, void* d_ws, size_t ws_size,
                              hipStream_t stream)
{
  const float* o = (const float*)d_in[0];  // [B, 2*NJ, 14, 14]
  const float* h = (const float*)d_in[1];  // [B, NJ, 14, 14]
  const float* t = (const float*)d_in[2];  // [B, NJ, 2]
  const float* v = (const float*)d_in[3];  // [B, NJ, 2]
  const int njoint = in_sizes[1] / TILE;          // B*NJ = 114688
  const int nblocks = (njoint + JPB - 1) / JPB;   // 1792

  float* part = (float*)d_ws;  // 2*nblocks floats, fully rewritten each call
  joint_kernel<<<nblocks, BLK, 0, stream>>>(o, h, t, v, part, njoint, nblocks);
  finalize_kernel<<<1, BLK, 0, stream>>>(part, (float*)d_out, nblocks);
}

// Round 10
// 29.263 us; speedup vs baseline: 1.7095x; 1.1864x over previous
//
#include <hip/hip_runtime.h>

// Problem constants: B=8192, NJ=14, COL=14, sigma=1, radius=4.
#define NJ    14
#define TILE  196          // 14*14 floats per tile (= 49 float4, 784 B)
#define BLK   256
#define JPB   64           // joints per block: lane = tile, wave = quarter
#define STAGE_DW (JPB * TILE)   // 12544 dwords = 50176 B staged per block

typedef __attribute__((address_space(1))) const void g_void;
typedef __attribute__((address_space(3))) void lds_void;

// exp(-0.5*d*d) with the 9-tap cutoff (|d|<=4), via v_exp_f32.
__device__ __forceinline__ float gtap(int d) {
  const int d2 = d * d;
  const float e = exp2f(-0.72134752044448169f * (float)d2);  // 0.5*log2(e)
  return (d2 <= 16) ? e : 0.0f;
}

// 1-D blurred-impulse response at position p for peak pk, with scipy
// 'reflect' padding folded in. Unnormalized (kernel-sum cancels in g/max).
__device__ __forceinline__ float uresp(int p, int pk) {
  float s = gtap(p - pk);
  if (p <= 3)  s += gtap(p + pk + 1);   // low reflection  (q<0 -> -1-q)
  if (p >= 10) s += gtap(27 - p - pk);  // high reflection (q>13 -> 27-q)
  return s;
}

__device__ __forceinline__ float wave_sum(float x) {
#pragma unroll
  for (int off = 32; off >= 1; off >>= 1) x += __shfl_xor(x, off);
  return x;
}

// Quarter K of one tile: float4 indices f = 4i + K (49 = 13+12+12+12).
// rowdot decomposition: rd[y] += h*ux[x] (1 fma/elem, compile-time y/x);
// cross = sum_y uy[y]*rd[y] folded at the end (14 fmas). All indices
// compile-time -> uy/ux/rd stay in registers (rule #20).
template<int K>
__device__ __forceinline__ void accum_part(const float4* __restrict__ hp,
    const float (&uy)[14], const float (&ux)[14],
    float& bm, int& bi, float& sh2, float& cross, float& q0)
{
  float rd[14] = {0,0,0,0,0,0,0,0,0,0,0,0,0,0};
  const int NI = (K == 0) ? 13 : 12;
#pragma unroll
  for (int i = 0; i < NI; ++i) {
    const int f = 4 * i + K;
    const float4 q = hp[f];            // ds_read_b128, stride 784B (bank-clean)
    const float qa[4] = {q.x, q.y, q.z, q.w};
#pragma unroll
    for (int c = 0; c < 4; ++c) {
      const int idx = 4 * f + c;
      const int y = idx / 14;
      const int x = idx - 14 * y;            // compile-time
      const float hv = qa[c];
      if (hv > bm) { bm = hv; bi = idx; }    // first-index within quarter
      sh2 = fmaf(hv, hv, sh2);
      if (y == 0) q0 = fmaf(hv, hv, q0);     // row-0 energy (invis fixup)
      rd[y] = fmaf(hv, ux[x], rd[y]);
    }
  }
#pragma unroll
  for (int y = 0; y < 14; ++y) cross = fmaf(uy[y], rd[y], cross);
}

__global__ __launch_bounds__(BLK, 3) void joint_kernel(
    const float* __restrict__ o, const float* __restrict__ h,
    const float* __restrict__ t, const float* __restrict__ v,
    float2* __restrict__ part)
{
  // 50176B stage buffer; reused (aliased) for the cross-wave reduction arrays.
  __shared__ __align__(16) float lds[STAGE_DW];

  const int tid  = threadIdx.x;
  const int lane = tid & 63;
  const int wid  = tid >> 6;
  const int jg   = blockIdx.x * JPB + lane;   // grid exact: 1792*64 = 114688

  // ---- coalesced global->LDS stage of this block's 64 tiles ----
  const float* gbase = h + (size_t)blockIdx.x * JPB * TILE;
#pragma unroll
  for (int i = 0; i < 13; ++i) {
    const int idx = i * BLK + tid;
    if (idx < JPB * 49) {
      __builtin_amdgcn_global_load_lds(
          (g_void*)(gbase + (size_t)idx * 4),       // per-lane global src
          (lds_void*)&lds[idx * 4],                 // uniform base + lane*16
          16, 0, 0);
    }
  }

  // ---- overlap: analytic 1-D responses while loads fly ----
  float uy[14], ux[14];
  const float2 tv = ((const float2*)t)[jg];
  const int xi = min(max((int)(tv.x * 14.0f), 0), 13);
  const int yi = min(max((int)(tv.y * 14.0f), 0), 13);
#pragma unroll
  for (int p = 0; p < 14; ++p) { uy[p] = uresp(p, yi); ux[p] = uresp(p, xi); }

  asm volatile("s_waitcnt vmcnt(0)" ::: "memory");
  __syncthreads();

  // ---- per-wave quarter pass over this lane's tile (divergence-free) ----
  float bm = -3.0e38f; int bi = 0;
  float sh2 = 0.0f, cross = 0.0f, q0 = 0.0f;
  {
    const float4* hp = (const float4*)&lds[lane * TILE];
    switch (wid) {   // wave-uniform branch: no lane divergence
      case 0: accum_part<0>(hp, uy, ux, bm, bi, sh2, cross, q0); break;
      case 1: accum_part<1>(hp, uy, ux, bm, bi, sh2, cross, q0); break;
      case 2: accum_part<2>(hp, uy, ux, bm, bi, sh2, cross, q0); break;
      default: accum_part<3>(hp, uy, ux, bm, bi, sh2, cross, q0); break;
    }
  }

  __syncthreads();   // all waves done READING tiles; safe to alias LDS
  float* red = lds;  // 5 arrays x 256 x 4B = 5120B, aliased into stage buffer
  red[0 * BLK + tid] = bm;
  ((int*)lds)[1 * BLK + tid] = bi;
  red[2 * BLK + tid] = sh2;
  red[3 * BLK + tid] = cross;
  red[4 * BLK + tid] = q0;
  __syncthreads();

  if (wid == 0) {
    // ---- combine the 4 quarters for this lane's joint ----
    float Bm = red[lane]; int Bi = ((int*)lds)[BLK + lane];
    float S2 = red[2 * BLK + lane], Cr = red[3 * BLK + lane], Q0 = red[4 * BLK + lane];
#pragma unroll
    for (int w = 1; w < 4; ++w) {
      const float m = red[w * 64 + lane];
      const int   i = ((int*)lds)[BLK + w * 64 + lane];
      if (m > Bm || (m == Bm && i < Bi)) { Bm = m; Bi = i; }  // global first-index
      S2 += red[2 * BLK + w * 64 + lane];
      Cr += red[3 * BLK + w * 64 + lane];
      Q0 += red[4 * BLK + w * 64 + lane];
    }

    const float2 vv = ((const float2*)v)[jg];
    const bool vis = ((int)vv.x) == 1;

    float Sy2 = 0.0f, Sx2 = 0.0f;
#pragma unroll
    for (int p = 0; p < 14; ++p) {
      Sy2 = fmaf(uy[p], uy[p], Sy2);
      Sx2 = fmaf(ux[p], ux[p], Sx2);
    }
    const float maxy = 1.0f + gtap(2 * yi + 1) + gtap(27 - 2 * yi);
    const float maxx = 1.0f + gtap(2 * xi + 1) + gtap(27 - 2 * xi);
    const float inv = vis ? (1.0f / (maxy * maxx)) : 0.0f;

    // sum(h-tt)^2 = S2 - 2*inv*Cr + inv^2*Sy2*Sx2 ; row0 zeroed if invis
    float s = S2 - 2.0f * inv * Cr + inv * inv * Sy2 * Sx2;
    if (!vis) s -= Q0;

    // ---- coordinate loss (argmax-dependent gather, stays global) ----
    const int b = jg / NJ;
    const int j = jg - b * NJ;
    const int yC = Bi / 14;
    const int xC = Bi - 14 * yC;
    const size_t ob = ((size_t)b * (2 * NJ) + j) * TILE + (size_t)Bi;
    const float ox = o[ob];
    const float oy = o[ob + (size_t)NJ * TILE];
    const bool cond = Bm > 0.5f;
    const float sc = 1.0f / 14.0f;
    const float px = cond ? (ox + (float)xC) * sc : 0.0f;
    const float py = cond ? (oy + (float)yC) * sc : 0.0f;
    const float d0 = (px - tv.x) * vv.x;
    const float d1 = (py - tv.y) * vv.y;
    s += d0 * d0 + d1 * d1;

    // ---- deterministic wave-0 reduction -> per-block partial ----
    const float S = wave_sum(s);
    const float N = wave_sum(vv.x + vv.y);
    if (lane == 0) part[blockIdx.x] = make_float2(S, N);
  }
}

__global__ __launch_bounds__(BLK) void finalize_kernel(
    const float2* __restrict__ part, float* __restrict__ out, int nblocks)
{
  float s = 0.0f, n = 0.0f;
  for (int i = threadIdx.x; i < nblocks; i += BLK) {
    const float2 p = part[i];       // coalesced float2 stream
    s += p.x;
    n += p.y;
  }
  s = wave_sum(s);
  n = wave_sum(n);
  __shared__ float rs[4], rn[4];
  const int lane = threadIdx.x & 63, wid = threadIdx.x >> 6;
  if (lane == 0) { rs[wid] = s; rn[wid] = n; }
  __syncthreads();
  if (threadIdx.x == 0) {
    const float S = rs[0] + rs[1] + rs[2] + rs[3];
    const float N = rn[0] + rn[1] + rn[2] + rn[3];
    out[0] = S / (0.5f * N);   // (d1_sum + d2_sum) / N1, N1 = sum(v)/2
  }
}

extern "C" void kernel_launch(void* const* d_in, const int* in_sizes, int n_in,
                              void* d_out, int out_size, void* d_ws, size_t ws_size,
                              hipStream_t stream)
{
  const float* o = (const float*)d_in[0];  // [B, 2*NJ, 14, 14]
  const float* h = (const float*)d_in[1];  // [B, NJ, 14, 14]
  const float* t = (const float*)d_in[2];  // [B, NJ, 2]
  const float* v = (const float*)d_in[3];  // [B, NJ, 2]
  const int njoint = in_sizes[1] / TILE;   // B*NJ = 114688 (= 1792*64 exact)
  const int nblocks = njoint / JPB;        // 1792

  float2* part = (float2*)d_ws;  // nblocks float2 = 14336B, rewritten each call
  joint_kernel<<<nblocks, BLK, 0, stream>>>(o, h, t, v, part);
  finalize_kernel<<<1, BLK, 0, stream>>>(part, (float*)d_out, nblocks);
}

// Round 11
// 28.743 us; speedup vs baseline: 1.7405x; 1.0181x over previous
//
#include <hip/hip_runtime.h>

// Problem constants: B=8192, NJ=14, COL=14, sigma=1, radius=4.
#define NJ    14
#define TILE  196          // 14*14 floats per tile (= 49 float4, 784 B)
#define BLK   256
#define JPB   64           // joints per block: lane = tile, wave = quarter
#define STAGE_DW (JPB * TILE)   // 12544 dwords = 50176 B staged per block

typedef __attribute__((address_space(1))) const void g_void;
typedef __attribute__((address_space(3))) void lds_void;

// exp(-0.5*d*d) with the 9-tap cutoff (|d|<=4), via v_exp_f32.
__device__ __forceinline__ float gtap(int d) {
  const int d2 = d * d;
  const float e = exp2f(-0.72134752044448169f * (float)d2);  // 0.5*log2(e)
  return (d2 <= 16) ? e : 0.0f;
}

// 1-D blurred-impulse response at position p for peak pk, with scipy
// 'reflect' padding folded in. Unnormalized (kernel-sum cancels in g/max).
__device__ __forceinline__ float uresp(int p, int pk) {
  float s = gtap(p - pk);
  if (p <= 3)  s += gtap(p + pk + 1);   // low reflection  (q<0 -> -1-q)
  if (p >= 10) s += gtap(27 - p - pk);  // high reflection (q>13 -> 27-q)
  return s;
}

__device__ __forceinline__ float wave_sum(float x) {
#pragma unroll
  for (int off = 32; off >= 1; off >>= 1) x += __shfl_xor(x, off);
  return x;
}

// Quarter K of one tile: float4 indices f = 4i + K (49 = 13+12+12+12).
// rowdot decomposition: rd[y] += h*ux[x] (1 fma/elem, compile-time y/x);
// cross = sum_y uy[y]*rd[y] folded at the end (14 fmas). All indices
// compile-time -> uy/ux/rd stay in registers (rule #20).
template<int K>
__device__ __forceinline__ void accum_part(const float4* __restrict__ hp,
    const float (&uy)[14], const float (&ux)[14],
    float& bm, int& bi, float& sh2, float& cross, float& q0)
{
  float rd[14] = {0,0,0,0,0,0,0,0,0,0,0,0,0,0};
  const int NI = (K == 0) ? 13 : 12;
#pragma unroll
  for (int i = 0; i < NI; ++i) {
    const int f = 4 * i + K;
    const float4 q = hp[f];            // ds_read_b128, stride 784B (bank-clean)
    const float qa[4] = {q.x, q.y, q.z, q.w};
#pragma unroll
    for (int c = 0; c < 4; ++c) {
      const int idx = 4 * f + c;
      const int y = idx / 14;
      const int x = idx - 14 * y;            // compile-time
      const float hv = qa[c];
      if (hv > bm) { bm = hv; bi = idx; }    // first-index within quarter
      sh2 = fmaf(hv, hv, sh2);
      if (y == 0) q0 = fmaf(hv, hv, q0);     // row-0 energy (invis fixup)
      rd[y] = fmaf(hv, ux[x], rd[y]);
    }
  }
#pragma unroll
  for (int y = 0; y < 14; ++y) cross = fmaf(uy[y], rd[y], cross);
}

__global__ __launch_bounds__(BLK, 3) void joint_kernel(
    const float* __restrict__ o, const float* __restrict__ h,
    const float* __restrict__ t, const float* __restrict__ v,
    float2* __restrict__ part)
{
  // 50176B stage buffer; reused (aliased) for the cross-wave reduction arrays.
  __shared__ __align__(16) float lds[STAGE_DW];
  __shared__ float rs[4], rn[4];   // dedicated (NOT aliased): live during epilogue

  const int tid  = threadIdx.x;
  const int lane = tid & 63;
  const int wid  = tid >> 6;
  const int jg   = blockIdx.x * JPB + lane;   // grid exact: 1792*64 = 114688

  // ---- coalesced global->LDS stage of this block's 64 tiles ----
  const float* gbase = h + (size_t)blockIdx.x * JPB * TILE;
#pragma unroll
  for (int i = 0; i < 13; ++i) {
    const int idx = i * BLK + tid;
    if (idx < JPB * 49) {
      __builtin_amdgcn_global_load_lds(
          (g_void*)(gbase + (size_t)idx * 4),       // per-lane global src
          (lds_void*)&lds[idx * 4],                 // uniform base + lane*16
          16, 0, 0);
    }
  }

  // ---- overlap: analytic 1-D responses while loads fly ----
  float uy[14], ux[14];
  const float2 tv = ((const float2*)t)[jg];
  const int xi = min(max((int)(tv.x * 14.0f), 0), 13);
  const int yi = min(max((int)(tv.y * 14.0f), 0), 13);
#pragma unroll
  for (int p = 0; p < 14; ++p) { uy[p] = uresp(p, yi); ux[p] = uresp(p, xi); }

  asm volatile("s_waitcnt vmcnt(0)" ::: "memory");
  __syncthreads();

  // ---- per-wave quarter pass over this lane's tile (divergence-free) ----
  float bm = -3.0e38f; int bi = 0;
  float sh2 = 0.0f, cross = 0.0f, q0 = 0.0f;
  {
    const float4* hp = (const float4*)&lds[lane * TILE];
    switch (wid) {   // wave-uniform branch: no lane divergence
      case 0: accum_part<0>(hp, uy, ux, bm, bi, sh2, cross, q0); break;
      case 1: accum_part<1>(hp, uy, ux, bm, bi, sh2, cross, q0); break;
      case 2: accum_part<2>(hp, uy, ux, bm, bi, sh2, cross, q0); break;
      default: accum_part<3>(hp, uy, ux, bm, bi, sh2, cross, q0); break;
    }
  }

  __syncthreads();   // all waves done READING tiles; safe to alias LDS
  float* red = lds;  // 5 arrays x 256 x 4B = 5120B, aliased into stage buffer
  red[0 * BLK + tid] = bm;
  ((int*)lds)[1 * BLK + tid] = bi;
  red[2 * BLK + tid] = sh2;
  red[3 * BLK + tid] = cross;
  red[4 * BLK + tid] = q0;
  __syncthreads();

  // ---- 4-way parallel epilogue: wave w handles joints [16w, 16w+16).
  // Lane L of EVERY wave holds uy/ux for joint L in registers, so wave w
  // activates lanes 16w..16w+15 (their registers match those joints).
  float s_acc = 0.0f, n_acc = 0.0f;
  if ((lane >> 4) == wid) {
    // ---- combine the 4 quarters for this lane's joint ----
    float Bm = red[lane]; int Bi = ((int*)lds)[BLK + lane];
    float S2 = red[2 * BLK + lane], Cr = red[3 * BLK + lane], Q0 = red[4 * BLK + lane];
#pragma unroll
    for (int w = 1; w < 4; ++w) {
      const float m = red[w * 64 + lane];
      const int   i = ((int*)lds)[BLK + w * 64 + lane];
      if (m > Bm || (m == Bm && i < Bi)) { Bm = m; Bi = i; }  // global first-index
      S2 += red[2 * BLK + w * 64 + lane];
      Cr += red[3 * BLK + w * 64 + lane];
      Q0 += red[4 * BLK + w * 64 + lane];
    }

    const float2 vv = ((const float2*)v)[jg];
    const bool vis = ((int)vv.x) == 1;

    float Sy2 = 0.0f, Sx2 = 0.0f;
#pragma unroll
    for (int p = 0; p < 14; ++p) {
      Sy2 = fmaf(uy[p], uy[p], Sy2);
      Sx2 = fmaf(ux[p], ux[p], Sx2);
    }
    const float maxy = 1.0f + gtap(2 * yi + 1) + gtap(27 - 2 * yi);
    const float maxx = 1.0f + gtap(2 * xi + 1) + gtap(27 - 2 * xi);
    const float inv = vis ? (1.0f / (maxy * maxx)) : 0.0f;

    // sum(h-tt)^2 = S2 - 2*inv*Cr + inv^2*Sy2*Sx2 ; row0 zeroed if invis
    float s = S2 - 2.0f * inv * Cr + inv * inv * Sy2 * Sx2;
    if (!vis) s -= Q0;

    // ---- coordinate loss (argmax-dependent gather, stays global) ----
    const int b = jg / NJ;
    const int j = jg - b * NJ;
    const int yC = Bi / 14;
    const int xC = Bi - 14 * yC;
    const size_t ob = ((size_t)b * (2 * NJ) + j) * TILE + (size_t)Bi;
    const float ox = o[ob];
    const float oy = o[ob + (size_t)NJ * TILE];
    const bool cond = Bm > 0.5f;
    const float sc = 1.0f / 14.0f;
    const float px = cond ? (ox + (float)xC) * sc : 0.0f;
    const float py = cond ? (oy + (float)yC) * sc : 0.0f;
    const float d0 = (px - tv.x) * vv.x;
    const float d1 = (py - tv.y) * vv.y;
    s += d0 * d0 + d1 * d1;

    s_acc = s;
    n_acc = vv.x + vv.y;
  }

  // ---- per-wave deterministic sum (inactive lanes contribute 0) ----
  s_acc = wave_sum(s_acc);
  n_acc = wave_sum(n_acc);
  if (lane == 0) { rs[wid] = s_acc; rn[wid] = n_acc; }
  __syncthreads();
  if (tid == 0) {
    const float S = rs[0] + rs[1] + rs[2] + rs[3];
    const float N = rn[0] + rn[1] + rn[2] + rn[3];
    part[blockIdx.x] = make_float2(S, N);
  }
}

#define FBLK 1024
__global__ __launch_bounds__(FBLK) void finalize_kernel(
    const float2* __restrict__ part, float* __restrict__ out, int nblocks)
{
  float s = 0.0f, n = 0.0f;
  for (int i = threadIdx.x; i < nblocks; i += FBLK) {   // 2 coalesced rounds
    const float2 p = part[i];
    s += p.x;
    n += p.y;
  }
  s = wave_sum(s);
  n = wave_sum(n);
  __shared__ float rs[16], rn[16];
  const int lane = threadIdx.x & 63, wid = threadIdx.x >> 6;
  if (lane == 0) { rs[wid] = s; rn[wid] = n; }
  __syncthreads();
  if (threadIdx.x == 0) {
    float S = 0.0f, N = 0.0f;
#pragma unroll
    for (int i = 0; i < 16; ++i) { S += rs[i]; N += rn[i]; }
    out[0] = S / (0.5f * N);   // (d1_sum + d2_sum) / N1, N1 = sum(v)/2
  }
}

extern "C" void kernel_launch(void* const* d_in, const int* in_sizes, int n_in,
                              void* d_out, int out_size, void* d_ws, size_t ws_size,
                              hipStream_t stream)
{
  const float* o = (const float*)d_in[0];  // [B, 2*NJ, 14, 14]
  const float* h = (const float*)d_in[1];  // [B, NJ, 14, 14]
  const float* t = (const float*)d_in[2];  // [B, NJ, 2]
  const float* v = (const float*)d_in[3];  // [B, NJ, 2]
  const int njoint = in_sizes[1] / TILE;   // B*NJ = 114688 (= 1792*64 exact)
  const int nblocks = njoint / JPB;        // 1792

  float2* part = (float2*)d_ws;  // nblocks float2 = 14336B, rewritten each call
  joint_kernel<<<nblocks, BLK, 0, stream>>>(o, h, t, v, part);
  finalize_kernel<<<1, FBLK, 0, stream>>>(part, (float*)d_out, nblocks);
}